// Round 4
// baseline (20.221 us; speedup 1.0000x reference)
//
#include <hip/hip_runtime.h>

#define NEGV (-9e15f)
#define LOG2E 1.44269504088896340736f

__device__ __forceinline__ float wsum(float v) {
#pragma unroll
    for (int off = 32; off > 0; off >>= 1) v += __shfl_xor(v, off, 64);
    return v;
}
__device__ __forceinline__ float wmax(float v) {
#pragma unroll
    for (int off = 32; off > 0; off >>= 1) v = fmaxf(v, __shfl_xor(v, off, 64));
    return v;
}
// reduce within 16-lane groups (enough when support is lanes 0..15)
__device__ __forceinline__ float hsum16(float v) {
#pragma unroll
    for (int off = 1; off < 16; off <<= 1) v += __shfl_xor(v, off, 64);
    return v;
}
__device__ __forceinline__ float bcast0(float v) {
    return __int_as_float(__builtin_amdgcn_readfirstlane(__float_as_int(v)));
}

__global__ __launch_bounds__(64) void sentinel_kernel(float* __restrict__ out) {
    out[blockIdx.x * 64 + threadIdx.x] = 111222.0f;
}

// 128 threads = 2 waves per (b,i) row; wave w owns j in [256w, 256w+256).
// bs=8, N=512, Fx=8, F=64, D=16. Inputs f32, adj int32 (int64 auto-probed),
// output f32. __launch_bounds__(128,8): target 8 waves/SIMD (VGPR<=64).
__global__ __launch_bounds__(128, 8) void gat_fused_f32(
    const float* __restrict__ input, const int* __restrict__ adj,
    const float* __restrict__ ext, const float* __restrict__ side,
    const float* __restrict__ W, const float* __restrict__ a,
    const float* __restrict__ WS, const float* __restrict__ aS,
    const float* __restrict__ WQ, const float* __restrict__ WK,
    const float* __restrict__ WV, float* __restrict__ out)
{
    const int N = 512, F = 64;
    const int lane = threadIdx.x & 63;
    const int w = threadIdx.x >> 6;
    const int b = blockIdx.x >> 9;
    const int i = blockIdx.x & (N - 1);

    __shared__ float red[8];

    // adj dtype probe (int32 vs int64 {0,1}); wave-uniform, deterministic.
    int probe = 0;
#pragma unroll
    for (int t = 0; t < 8; t++) probe |= adj[2 * (lane * 8 + t) + 1];
    const bool adj64 = (__any(probe != 0) == 0);

    // ---- weight contractions; log2e folded so all exp() become raw v_exp_f32.
    // lrelu is positively homogeneous and the >0 masks are scale-invariant, so
    // computing logits pre-scaled by log2e is exact.
    const float wf  = W[lane];
    const float wvf = WV[lane];
    const float c1  = wsum(wf * a[lane]) * LOG2E;
    const float c2  = wsum(wf * a[F + lane]) * LOG2E;
    const float wsf = WS[lane];
    const float cS1 = wsum(wsf * aS[lane]) * LOG2E;
    const float cS2 = wsum(wsf * aS[F + lane]) * LOG2E;
    float q0 = 0.f, q1 = 0.f, k0 = 0.f, k1 = 0.f;
    if (lane < 16) {
        q0 = WQ[lane]; q1 = WQ[16 + lane];
        k0 = WK[lane]; k1 = WK[16 + lane];
    }
    const float QS = 0.25f * LOG2E;  // 1/sqrt(D)=0.25 and log2e folded in
    const float a00 = bcast0(hsum16(q0 * k0)) * QS;
    const float a01 = bcast0(hsum16(q0 * k1)) * QS;
    const float a10 = bcast0(hsum16(q1 * k0)) * QS;
    const float a11 = bcast0(hsum16(q1 * k1)) * QS;

    const int row = b * N + i;
    const float x_i = input[row];
    const float y_i = side[row];

    float exti[8];
    {
        const float4 e0 = ((const float4*)(ext + row * 8))[0];
        const float4 e1 = ((const float4*)(ext + row * 8))[1];
        exti[0] = e0.x; exti[1] = e0.y; exti[2] = e0.z; exti[3] = e0.w;
        exti[4] = e1.x; exti[5] = e1.y; exti[6] = e1.z; exti[7] = e1.w;
    }

    const float s1i  = c1 * x_i;
    const float sS1i = cS1 * y_i;
    const int jbase = 256 * w;
    const float* xp = input + b * N + jbase;
    const float* yp = side + b * N + jbase;
    const int arow = i * N + jbase;

    // ---- pass 1: this wave's 256 logits, split softmax stats via LDS ----
    float L[4], xj[4];
#pragma unroll
    for (int t = 0; t < 4; t++) {
        const int jj = lane + 64 * t;
        const float xv = xp[jj];
        const float yv = yp[jj];
        xj[t] = xv;
        float z  = s1i + c2 * xv;   z  = fmaxf(z, 0.2f * z);   // lrelu
        float zs = sS1i + cS2 * yv; zs = fmaxf(zs, 0.2f * zs);
        const float v = z + zs;
        const int am = adj64 ? (adj[2 * (arow + jj)] | adj[2 * (arow + jj) + 1])
                             : adj[arow + jj];
        L[t] = (am != 0 && v > 0.f) ? v : NEGV;
    }
    float M = fmaxf(fmaxf(L[0], L[1]), fmaxf(L[2], L[3]));
    M = wmax(M);
    if (lane == 0) red[w] = M;
    __syncthreads();
    M = fmaxf(red[0], red[1]);

    float E[4]; float s = 0.f;
#pragma unroll
    for (int t = 0; t < 4; t++) { E[t] = __builtin_amdgcn_exp2f(L[t] - M); s += E[t]; }
    s = wsum(s);
    if (lane == 0) red[2 + w] = s;
    __syncthreads();
    const float inv = __builtin_amdgcn_rcpf(red[2] + red[3]);

    // ---- pass 2: A_partial = sum E*x_j ; R_partial = sum E * <sm_f, ext_i> ----
    float A = 0.f, Rp = 0.f;
#pragma unroll
    for (int t = 0; t < 4; t++) {
        const int jj = lane + 64 * t;
        float extj[8];
        {
            const float* ep = ext + (size_t)(b * N + jbase + jj) * 8;
            const float4 f0 = ((const float4*)ep)[0];
            const float4 f1 = ((const float4*)ep)[1];
            extj[0] = f0.x; extj[1] = f0.y; extj[2] = f0.z; extj[3] = f0.w;
            extj[4] = f1.x; extj[5] = f1.y; extj[6] = f1.z; extj[7] = f1.w;
        }
        const float qk0 = x_i * a00 + xj[t] * a10;   // pre-scaled by 0.25*log2e
        const float qk1 = x_i * a01 + xj[t] * a11;

        float d[8]; float dm = NEGV;
#pragma unroll
        for (int f = 0; f < 8; f++) {
            float dv = exti[f] * qk0 + extj[f] * qk1;
            dv = (dv > 0.f) ? dv : NEGV;
            d[f] = dv;
            dm = fmaxf(dm, dv);
        }
        float dsum = 0.f, dot = 0.f;
#pragma unroll
        for (int f = 0; f < 8; f++) {
            const float ef = __builtin_amdgcn_exp2f(d[f] - dm);
            dsum += ef;
            dot  += ef * exti[f];
        }
        A  += E[t] * xj[t];
        Rp += E[t] * __builtin_amdgcn_rcpf(dsum) * dot;
    }
    A  = wsum(A);
    Rp = wsum(Rp);
    if (lane == 0) { red[4 + w] = A; red[6 + w] = Rp; }
    __syncthreads();

    // ---- epilogue: wave 0 writes elu(h_prime), wave 1 writes elu(ext_rep) ----
    if (w == 0) {
        float o0 = (red[4] + red[5]) * inv * wf;
        o0 = (o0 > 0.f) ? o0 : expm1f(o0);
        out[row * F + lane] = o0;
    } else {
        float o1 = (red[6] + red[7]) * inv * wvf;
        o1 = (o1 > 0.f) ? o1 : expm1f(o1);
        out[8 * N * F + row * F + lane] = o1;
    }
}

extern "C" void kernel_launch(void* const* d_in, const int* in_sizes, int n_in,
                              void* d_out, int out_size, void* d_ws, size_t ws_size,
                              hipStream_t stream) {
    static const int exp_sizes[11] = {4096, 262144, 32768, 4096, 64, 128, 64, 128, 32, 32, 64};
    bool ok = (n_in == 11) && (out_size == 524288);
    if (ok) {
        for (int k = 0; k < 11; k++) if (in_sizes[k] != exp_sizes[k]) ok = false;
    }
    if (!ok) {
        sentinel_kernel<<<4096, 64, 0, stream>>>((float*)d_out);
        return;
    }

    gat_fused_f32<<<4096, 128, 0, stream>>>(
        (const float*)d_in[0], (const int*)d_in[1],
        (const float*)d_in[2], (const float*)d_in[3],
        (const float*)d_in[4], (const float*)d_in[5],
        (const float*)d_in[6], (const float*)d_in[7],
        (const float*)d_in[8], (const float*)d_in[9],
        (const float*)d_in[10],
        (float*)d_out);
}

// Round 5
// 15.533 us; speedup vs baseline: 1.3018x; 1.3018x over previous
//
#include <hip/hip_runtime.h>

#define NEGV (-9e15f)
#define LOG2E 1.44269504088896340736f

__device__ __forceinline__ float wsum(float v) {
#pragma unroll
    for (int off = 32; off > 0; off >>= 1) v += __shfl_xor(v, off, 64);
    return v;
}
__device__ __forceinline__ float wmax(float v) {
#pragma unroll
    for (int off = 32; off > 0; off >>= 1) v = fmaxf(v, __shfl_xor(v, off, 64));
    return v;
}
__device__ __forceinline__ float hsum16(float v) {
#pragma unroll
    for (int off = 1; off < 16; off <<= 1) v += __shfl_xor(v, off, 64);
    return v;
}
__device__ __forceinline__ float bcast0(float v) {
    return __int_as_float(__builtin_amdgcn_readfirstlane(__float_as_int(v)));
}
__device__ __forceinline__ void ld8f(const float* p, float* o) {
    const float4 v0 = ((const float4*)p)[0];
    const float4 v1 = ((const float4*)p)[1];
    o[0] = v0.x; o[1] = v0.y; o[2] = v0.z; o[3] = v0.w;
    o[4] = v1.x; o[5] = v1.y; o[6] = v1.z; o[7] = v1.w;
}

__global__ __launch_bounds__(64) void sentinel_kernel(float* __restrict__ out) {
    out[blockIdx.x * 64 + threadIdx.x] = 111222.0f;
}

// One wave (64 threads) handles TWO adjacent rows (b,i0),(b,i0+1).
// Shares all j-data loads between the rows; no LDS, no barriers.
// bs=8, N=512, Fx=8, F=64, D=16. Inputs f32, adj int32 (int64 auto-probe),
// output f32. Grid 2048x64 -> 8 waves/CU (2/SIMD), latency hidden by 2-row ILP.
__global__ __launch_bounds__(64, 2) void gat_fused_f32(
    const float* __restrict__ input, const int* __restrict__ adj,
    const float* __restrict__ ext, const float* __restrict__ side,
    const float* __restrict__ W, const float* __restrict__ a,
    const float* __restrict__ WS, const float* __restrict__ aS,
    const float* __restrict__ WQ, const float* __restrict__ WK,
    const float* __restrict__ WV, float* __restrict__ out)
{
    const int N = 512, F = 64;
    const int lane = threadIdx.x;
    const int b = blockIdx.x >> 8;
    const int i0 = (blockIdx.x & 255) * 2;

    // adj dtype probe: one load covering the high words of int64-entries 0..63.
    // int64 {0,1} -> all zero; int32 random 0/1 -> P(all zero) = 2^-64.
    const bool adj64 = (__any(adj[2 * lane + 1] != 0) == 0);

    // ---- per-wave weight contractions (log2e folded; lrelu is pos-homogeneous,
    // masks are scale-invariant, softmax via exp2 is exact) ----
    const float wf  = W[lane];
    const float wvf = WV[lane];
    const float c1  = wsum(wf * a[lane]) * LOG2E;
    const float c2  = wsum(wf * a[F + lane]) * LOG2E;
    const float wsf = WS[lane];
    const float cS1 = wsum(wsf * aS[lane]) * LOG2E;
    const float cS2 = wsum(wsf * aS[F + lane]) * LOG2E;
    float q0 = 0.f, q1 = 0.f, k0 = 0.f, k1 = 0.f;
    if (lane < 16) {
        q0 = WQ[lane]; q1 = WQ[16 + lane];
        k0 = WK[lane]; k1 = WK[16 + lane];
    }
    const float QS = 0.25f * LOG2E;  // 1/sqrt(16) and log2e folded
    const float a00 = bcast0(hsum16(q0 * k0)) * QS;
    const float a01 = bcast0(hsum16(q0 * k1)) * QS;
    const float a10 = bcast0(hsum16(q1 * k0)) * QS;
    const float a11 = bcast0(hsum16(q1 * k1)) * QS;

    const int row0 = b * N + i0;
    const float x0 = input[row0], x1 = input[row0 + 1];
    const float y0 = side[row0],  y1 = side[row0 + 1];
    float ei0[8], ei1[8];
    ld8f(ext + (size_t)row0 * 8, ei0);
    ld8f(ext + (size_t)(row0 + 1) * 8, ei1);

    const float s10 = c1 * x0,  s11 = c1 * x1;
    const float t10 = cS1 * y0, t11 = cS1 * y1;

    const float* xp = input + b * N;
    const float* yp = side + b * N;
    const int* adji0 = adj + i0 * N;
    const int* adji1 = adji0 + N;
    const long long* adjl0 = (const long long*)adj + (size_t)i0 * N;
    const long long* adjl1 = adjl0 + N;

    // ---- pass 1: logits for both rows; j-data loaded once ----
    float xj[8], L0[8], L1[8];
#pragma unroll
    for (int t = 0; t < 8; t++) {
        const int jj = lane + 64 * t;
        const float xv = xp[jj];
        const float yv = yp[jj];
        xj[t] = xv;
        const float z  = c2 * xv;
        const float zs = cS2 * yv;
        float u0 = s10 + z;  u0 = fmaxf(u0, 0.2f * u0);
        float v0 = t10 + zs; v0 = fmaxf(v0, 0.2f * v0);
        float u1 = s11 + z;  u1 = fmaxf(u1, 0.2f * u1);
        float v1 = t11 + zs; v1 = fmaxf(v1, 0.2f * v1);
        const float w0 = u0 + v0;
        const float w1 = u1 + v1;
        int m0, m1;
        if (adj64) { m0 = (adjl0[jj] != 0); m1 = (adjl1[jj] != 0); }
        else       { m0 = adji0[jj];        m1 = adji1[jj]; }
        L0[t] = (m0 != 0 && w0 > 0.f) ? w0 : NEGV;
        L1[t] = (m1 != 0 && w1 > 0.f) ? w1 : NEGV;
    }
    float M0 = L0[0], M1 = L1[0];
#pragma unroll
    for (int t = 1; t < 8; t++) { M0 = fmaxf(M0, L0[t]); M1 = fmaxf(M1, L1[t]); }
    M0 = wmax(M0); M1 = wmax(M1);

    float s0 = 0.f, s1 = 0.f;
#pragma unroll
    for (int t = 0; t < 8; t++) {
        L0[t] = __builtin_amdgcn_exp2f(L0[t] - M0); s0 += L0[t];  // L now holds E
        L1[t] = __builtin_amdgcn_exp2f(L1[t] - M1); s1 += L1[t];
    }
    const float inv0 = __builtin_amdgcn_rcpf(wsum(s0));
    const float inv1 = __builtin_amdgcn_rcpf(wsum(s1));

    // ---- pass 2: A_r = sum E_r x_j ; R_r = sum E_r <sm_f, ext_i_r> ----
    float A0 = 0.f, A1 = 0.f, R0 = 0.f, R1 = 0.f;
#pragma unroll
    for (int t = 0; t < 8; t++) {
        const int jj = lane + 64 * t;
        float ej[8];
        ld8f(ext + (size_t)(b * N + jj) * 8, ej);
        const float qj0 = xj[t] * a10, qj1 = xj[t] * a11;
        const float qk00 = x0 * a00 + qj0, qk01 = x0 * a01 + qj1;
        const float qk10 = x1 * a00 + qj0, qk11 = x1 * a01 + qj1;

        float d0[8], d1[8];
        float dm0 = NEGV, dm1 = NEGV;
#pragma unroll
        for (int f = 0; f < 8; f++) {
            float dv0 = ei0[f] * qk00 + ej[f] * qk01;
            float dv1 = ei1[f] * qk10 + ej[f] * qk11;
            dv0 = (dv0 > 0.f) ? dv0 : NEGV;
            dv1 = (dv1 > 0.f) ? dv1 : NEGV;
            d0[f] = dv0; dm0 = fmaxf(dm0, dv0);
            d1[f] = dv1; dm1 = fmaxf(dm1, dv1);
        }
        float ds0 = 0.f, ds1 = 0.f, dot0 = 0.f, dot1 = 0.f;
#pragma unroll
        for (int f = 0; f < 8; f++) {
            const float e0 = __builtin_amdgcn_exp2f(d0[f] - dm0);
            const float e1 = __builtin_amdgcn_exp2f(d1[f] - dm1);
            ds0 += e0; dot0 += e0 * ei0[f];
            ds1 += e1; dot1 += e1 * ei1[f];
        }
        A0 += L0[t] * xj[t];
        A1 += L1[t] * xj[t];
        R0 += L0[t] * __builtin_amdgcn_rcpf(ds0) * dot0;
        R1 += L1[t] * __builtin_amdgcn_rcpf(ds1) * dot1;
    }
    A0 = wsum(A0); A1 = wsum(A1);
    R0 = wsum(R0); R1 = wsum(R1);

    // ---- epilogue: elu(x) = x>0 ? x : 2^(x*log2e)-1 ----
    const int o = row0 * F + lane;
    float o00 = A0 * inv0 * wf;
    float o01 = A1 * inv1 * wf;
    float o10 = R0 * inv0 * wvf;
    float o11 = R1 * inv1 * wvf;
    o00 = (o00 > 0.f) ? o00 : (__builtin_amdgcn_exp2f(o00 * LOG2E) - 1.f);
    o01 = (o01 > 0.f) ? o01 : (__builtin_amdgcn_exp2f(o01 * LOG2E) - 1.f);
    o10 = (o10 > 0.f) ? o10 : (__builtin_amdgcn_exp2f(o10 * LOG2E) - 1.f);
    o11 = (o11 > 0.f) ? o11 : (__builtin_amdgcn_exp2f(o11 * LOG2E) - 1.f);
    out[o] = o00;
    out[o + F] = o01;
    out[262144 + o] = o10;          // 8*N*F = 262144
    out[262144 + o + F] = o11;
}

extern "C" void kernel_launch(void* const* d_in, const int* in_sizes, int n_in,
                              void* d_out, int out_size, void* d_ws, size_t ws_size,
                              hipStream_t stream) {
    static const int exp_sizes[11] = {4096, 262144, 32768, 4096, 64, 128, 64, 128, 32, 32, 64};
    bool ok = (n_in == 11) && (out_size == 524288);
    if (ok) {
        for (int k = 0; k < 11; k++) if (in_sizes[k] != exp_sizes[k]) ok = false;
    }
    if (!ok) {
        sentinel_kernel<<<4096, 64, 0, stream>>>((float*)d_out);
        return;
    }

    gat_fused_f32<<<2048, 64, 0, stream>>>(
        (const float*)d_in[0], (const int*)d_in[1],
        (const float*)d_in[2], (const float*)d_in[3],
        (const float*)d_in[4], (const float*)d_in[5],
        (const float*)d_in[6], (const float*)d_in[7],
        (const float*)d_in[8], (const float*)d_in[9],
        (const float*)d_in[10],
        (float*)d_out);
}

// Round 6
// 15.175 us; speedup vs baseline: 1.3325x; 1.0236x over previous
//
#include <hip/hip_runtime.h>

#define NEGV (-9e15f)
#define LOG2E 1.44269504088896340736f

__device__ __forceinline__ float wsum(float v) {
#pragma unroll
    for (int off = 32; off > 0; off >>= 1) v += __shfl_xor(v, off, 64);
    return v;
}
__device__ __forceinline__ float wmax(float v) {
#pragma unroll
    for (int off = 32; off > 0; off >>= 1) v = fmaxf(v, __shfl_xor(v, off, 64));
    return v;
}
__device__ __forceinline__ float hsum16(float v) {
#pragma unroll
    for (int off = 1; off < 16; off <<= 1) v += __shfl_xor(v, off, 64);
    return v;
}
__device__ __forceinline__ float bcast0(float v) {
    return __int_as_float(__builtin_amdgcn_readfirstlane(__float_as_int(v)));
}
__device__ __forceinline__ void ld8f(const float* p, float* o) {
    const float4 v0 = ((const float4*)p)[0];
    const float4 v1 = ((const float4*)p)[1];
    o[0] = v0.x; o[1] = v0.y; o[2] = v0.z; o[3] = v0.w;
    o[4] = v1.x; o[5] = v1.y; o[6] = v1.z; o[7] = v1.w;
}

__global__ __launch_bounds__(64) void sentinel_kernel(float* __restrict__ out) {
    out[blockIdx.x * 64 + threadIdx.x] = 111222.0f;
}

// Block = 128 threads = 2 waves, handles TWO adjacent rows (b,i0),(b,i0+1).
// Wave w owns j in [256w, 256w+256) FULLY INDEPENDENTLY (own softmax stats),
// merged at the end via exact online-softmax rescale: one barrier total.
// Each wave stages its ext half transposed [f][j] in its own LDS region
// (global loads issued at entry, land under preamble+pass1; conflict-free
// ds accesses) so pass-2 inner loads are LDS, not L2-latency chains.
// Inputs f32, adj int32 (int64 auto-probe), output f32.
__global__ __launch_bounds__(128, 4) void gat_fused_f32(
    const float* __restrict__ input, const int* __restrict__ adj,
    const float* __restrict__ ext, const float* __restrict__ side,
    const float* __restrict__ W, const float* __restrict__ a,
    const float* __restrict__ WS, const float* __restrict__ aS,
    const float* __restrict__ WQ, const float* __restrict__ WK,
    const float* __restrict__ WV, float* __restrict__ out)
{
    const int N = 512, F = 64;
    const int lane = threadIdx.x & 63;
    const int w = threadIdx.x >> 6;
    const int b = blockIdx.x >> 8;
    const int i0 = (blockIdx.x & 255) * 2;

    __shared__ float exts[2][8][256];   // per-wave transposed ext half, 16 KB
    __shared__ float mrg[16];           // cross-wave merge scratch

    const int jbase = 256 * w;

    // ---- issue ext-half staging loads NOW; consumed after pass 1 ----
    const float* ebase = ext + (size_t)(b * N + jbase) * 8;
    float4 stA[4], stB[4];
#pragma unroll
    for (int u = 0; u < 4; u++) {
        const float* p = ebase + (size_t)(u * 64 + lane) * 8;
        stA[u] = ((const float4*)p)[0];
        stB[u] = ((const float4*)p)[1];
    }

    // adj dtype probe: high words of int64-entries 0..63 (P_false = 2^-64).
    const bool adj64 = (__any(adj[2 * lane + 1] != 0) == 0);

    // ---- weight contractions (log2e folded; exact for lrelu/masks) ----
    const float wf  = W[lane];
    const float wvf = WV[lane];
    const float c1  = wsum(wf * a[lane]) * LOG2E;
    const float c2  = wsum(wf * a[F + lane]) * LOG2E;
    const float wsf = WS[lane];
    const float cS1 = wsum(wsf * aS[lane]) * LOG2E;
    const float cS2 = wsum(wsf * aS[F + lane]) * LOG2E;
    float q0 = 0.f, q1 = 0.f, k0 = 0.f, k1 = 0.f;
    if (lane < 16) {
        q0 = WQ[lane]; q1 = WQ[16 + lane];
        k0 = WK[lane]; k1 = WK[16 + lane];
    }
    const float QS = 0.25f * LOG2E;
    const float a00 = bcast0(hsum16(q0 * k0)) * QS;
    const float a01 = bcast0(hsum16(q0 * k1)) * QS;
    const float a10 = bcast0(hsum16(q1 * k0)) * QS;
    const float a11 = bcast0(hsum16(q1 * k1)) * QS;

    const int row0 = b * N + i0;
    const float x0 = input[row0], x1 = input[row0 + 1];
    const float y0 = side[row0],  y1 = side[row0 + 1];
    float ei0[8], ei1[8];
    ld8f(ext + (size_t)row0 * 8, ei0);
    ld8f(ext + (size_t)(row0 + 1) * 8, ei1);

    const float s10 = c1 * x0,  s11 = c1 * x1;
    const float t10 = cS1 * y0, t11 = cS1 * y1;

    const float* xp = input + b * N + jbase;
    const float* yp = side + b * N + jbase;
    const int arow0 = i0 * N + jbase;
    const int* adji0 = adj + arow0;
    const int* adji1 = adji0 + N;
    const long long* adjl0 = (const long long*)adj + arow0;
    const long long* adjl1 = adjl0 + N;

    // ---- pass 1: this wave's 256 logits for both rows ----
    float xj[4], L0[4], L1[4];
#pragma unroll
    for (int t = 0; t < 4; t++) {
        const int jj = lane + 64 * t;
        const float xv = xp[jj];
        const float yv = yp[jj];
        xj[t] = xv;
        const float z  = c2 * xv;
        const float zs = cS2 * yv;
        float u0 = s10 + z;  u0 = fmaxf(u0, 0.2f * u0);
        float v0 = t10 + zs; v0 = fmaxf(v0, 0.2f * v0);
        float u1 = s11 + z;  u1 = fmaxf(u1, 0.2f * u1);
        float v1 = t11 + zs; v1 = fmaxf(v1, 0.2f * v1);
        const float g0 = u0 + v0;
        const float g1 = u1 + v1;
        int m0, m1;
        if (adj64) { m0 = (adjl0[jj] != 0); m1 = (adjl1[jj] != 0); }
        else       { m0 = adji0[jj];        m1 = adji1[jj]; }
        L0[t] = (m0 != 0 && g0 > 0.f) ? g0 : NEGV;
        L1[t] = (m1 != 0 && g1 > 0.f) ? g1 : NEGV;
    }
    float M0 = fmaxf(fmaxf(L0[0], L0[1]), fmaxf(L0[2], L0[3]));
    float M1 = fmaxf(fmaxf(L1[0], L1[1]), fmaxf(L1[2], L1[3]));
    M0 = wmax(M0); M1 = wmax(M1);

    float s0 = 0.f, s1 = 0.f;
#pragma unroll
    for (int t = 0; t < 4; t++) {
        L0[t] = __builtin_amdgcn_exp2f(L0[t] - M0); s0 += L0[t];  // L := E
        L1[t] = __builtin_amdgcn_exp2f(L1[t] - M1); s1 += L1[t];
    }
    s0 = wsum(s0); s1 = wsum(s1);

    // ---- staged ext -> transposed LDS (own region; wave-local, no barrier) ----
#pragma unroll
    for (int u = 0; u < 4; u++) {
        const int r = u * 64 + lane;
        exts[w][0][r] = stA[u].x;
        exts[w][1][r] = stA[u].y;
        exts[w][2][r] = stA[u].z;
        exts[w][3][r] = stA[u].w;
        exts[w][4][r] = stB[u].x;
        exts[w][5][r] = stB[u].y;
        exts[w][6][r] = stB[u].z;
        exts[w][7][r] = stB[u].w;
    }

    // ---- pass 2: unnormalized A_w, R_w over this wave's half ----
    float A0 = 0.f, A1 = 0.f, R0 = 0.f, R1 = 0.f;
#pragma unroll
    for (int t = 0; t < 4; t++) {
        const int jj = lane + 64 * t;
        float ej[8];
#pragma unroll
        for (int f = 0; f < 8; f++) ej[f] = exts[w][f][jj];

        const float qj0 = xj[t] * a10, qj1 = xj[t] * a11;
        const float qk00 = x0 * a00 + qj0, qk01 = x0 * a01 + qj1;
        const float qk10 = x1 * a00 + qj0, qk11 = x1 * a01 + qj1;

        float d0[8], d1[8];
        float dm0 = NEGV, dm1 = NEGV;
#pragma unroll
        for (int f = 0; f < 8; f++) {
            float dv0 = ei0[f] * qk00 + ej[f] * qk01;
            float dv1 = ei1[f] * qk10 + ej[f] * qk11;
            dv0 = (dv0 > 0.f) ? dv0 : NEGV;
            dv1 = (dv1 > 0.f) ? dv1 : NEGV;
            d0[f] = dv0; dm0 = fmaxf(dm0, dv0);
            d1[f] = dv1; dm1 = fmaxf(dm1, dv1);
        }
        float ds0 = 0.f, ds1 = 0.f, dot0 = 0.f, dot1 = 0.f;
#pragma unroll
        for (int f = 0; f < 8; f++) {
            const float e0 = __builtin_amdgcn_exp2f(d0[f] - dm0);
            const float e1 = __builtin_amdgcn_exp2f(d1[f] - dm1);
            ds0 += e0; dot0 += e0 * ei0[f];
            ds1 += e1; dot1 += e1 * ei1[f];
        }
        A0 += L0[t] * xj[t];
        A1 += L1[t] * xj[t];
        R0 += L0[t] * __builtin_amdgcn_rcpf(ds0) * dot0;
        R1 += L1[t] * __builtin_amdgcn_rcpf(ds1) * dot1;
    }
    A0 = wsum(A0); A1 = wsum(A1);
    R0 = wsum(R0); R1 = wsum(R1);

    // ---- cross-wave online-softmax merge (exact): one barrier ----
    if (lane == 0) {
        float* m = mrg + w * 8;
        m[0] = M0; m[1] = M1; m[2] = s0; m[3] = s1;
        m[4] = A0; m[5] = A1; m[6] = R0; m[7] = R1;
    }
    __syncthreads();

    const float Ma0 = fmaxf(mrg[0], mrg[8]);
    const float Ma1 = fmaxf(mrg[1], mrg[9]);
    const float p00 = __builtin_amdgcn_exp2f(mrg[0] - Ma0);  // NEGV-NEGV=0 -> 1
    const float p01 = __builtin_amdgcn_exp2f(mrg[8] - Ma0);
    const float p10 = __builtin_amdgcn_exp2f(mrg[1] - Ma1);
    const float p11 = __builtin_amdgcn_exp2f(mrg[9] - Ma1);
    const float inv0 = __builtin_amdgcn_rcpf(p00 * mrg[2] + p01 * mrg[10]);
    const float inv1 = __builtin_amdgcn_rcpf(p10 * mrg[3] + p11 * mrg[11]);

    const int o = row0 * F + lane;
    if (w == 0) {
        float o00 = (p00 * mrg[4] + p01 * mrg[12]) * inv0 * wf;
        float o01 = (p10 * mrg[5] + p11 * mrg[13]) * inv1 * wf;
        o00 = (o00 > 0.f) ? o00 : (__builtin_amdgcn_exp2f(o00 * LOG2E) - 1.f);
        o01 = (o01 > 0.f) ? o01 : (__builtin_amdgcn_exp2f(o01 * LOG2E) - 1.f);
        out[o] = o00;
        out[o + F] = o01;
    } else {
        float o10 = (p00 * mrg[6] + p01 * mrg[14]) * inv0 * wvf;
        float o11 = (p10 * mrg[7] + p11 * mrg[15]) * inv1 * wvf;
        o10 = (o10 > 0.f) ? o10 : (__builtin_amdgcn_exp2f(o10 * LOG2E) - 1.f);
        o11 = (o11 > 0.f) ? o11 : (__builtin_amdgcn_exp2f(o11 * LOG2E) - 1.f);
        out[262144 + o] = o10;      // 8*N*F = 262144
        out[262144 + o + F] = o11;
    }
}

extern "C" void kernel_launch(void* const* d_in, const int* in_sizes, int n_in,
                              void* d_out, int out_size, void* d_ws, size_t ws_size,
                              hipStream_t stream) {
    static const int exp_sizes[11] = {4096, 262144, 32768, 4096, 64, 128, 64, 128, 32, 32, 64};
    bool ok = (n_in == 11) && (out_size == 524288);
    if (ok) {
        for (int k = 0; k < 11; k++) if (in_sizes[k] != exp_sizes[k]) ok = false;
    }
    if (!ok) {
        sentinel_kernel<<<4096, 64, 0, stream>>>((float*)d_out);
        return;
    }

    gat_fused_f32<<<2048, 128, 0, stream>>>(
        (const float*)d_in[0], (const int*)d_in[1],
        (const float*)d_in[2], (const float*)d_in[3],
        (const float*)d_in[4], (const float*)d_in[5],
        (const float*)d_in[6], (const float*)d_in[7],
        (const float*)d_in[8], (const float*)d_in[9],
        (const float*)d_in[10],
        (float*)d_out);
}

// Round 7
// 14.951 us; speedup vs baseline: 1.3525x; 1.0150x over previous
//
#include <hip/hip_runtime.h>

#define NEGV (-9e15f)
#define LOG2E 1.44269504088896340736f

__device__ __forceinline__ float wsum(float v) {
#pragma unroll
    for (int off = 32; off > 0; off >>= 1) v += __shfl_xor(v, off, 64);
    return v;
}
__device__ __forceinline__ float wmax(float v) {
#pragma unroll
    for (int off = 32; off > 0; off >>= 1) v = fmaxf(v, __shfl_xor(v, off, 64));
    return v;
}
__device__ __forceinline__ float hsum16(float v) {
#pragma unroll
    for (int off = 1; off < 16; off <<= 1) v += __shfl_xor(v, off, 64);
    return v;
}
__device__ __forceinline__ void ld8f(const float* p, float* o) {
    const float4 v0 = ((const float4*)p)[0];
    const float4 v1 = ((const float4*)p)[1];
    o[0] = v0.x; o[1] = v0.y; o[2] = v0.z; o[3] = v0.w;
    o[4] = v1.x; o[5] = v1.y; o[6] = v1.z; o[7] = v1.w;
}

__global__ __launch_bounds__(64) void sentinel_kernel(float* __restrict__ out) {
    out[blockIdx.x * 64 + threadIdx.x] = 111222.0f;
}

// Block = 128 threads = 2 waves, two adjacent rows (b,i0),(b,i0+1).
// Wave w owns j in [256w,256w+256) independently; end-merge via exact
// online-softmax rescale (one barrier, 16-float LDS).
// ext[j] for this wave's j's is loaded ONCE into registers at entry
// (stA/stB) and consumed directly in pass 2 — no LDS roundtrip: lane's
// pass-2 j (jj=lane+64t) is exactly the j it loaded (j=jbase+64u+lane).
// Inputs f32, adj int32 (int64 auto-probe), output f32.
__global__ __launch_bounds__(128, 4) void gat_fused_f32(
    const float* __restrict__ input, const int* __restrict__ adj,
    const float* __restrict__ ext, const float* __restrict__ side,
    const float* __restrict__ W, const float* __restrict__ a,
    const float* __restrict__ WS, const float* __restrict__ aS,
    const float* __restrict__ WQ, const float* __restrict__ WK,
    const float* __restrict__ WV, float* __restrict__ out)
{
    const int N = 512, F = 64;
    const int lane = threadIdx.x & 63;
    const int w = threadIdx.x >> 6;
    const int b = blockIdx.x >> 8;
    const int i0 = (blockIdx.x & 255) * 2;

    __shared__ float mrg[16];

    const int jbase = 256 * w;

    // ---- issue this wave's ext loads NOW; consumed in pass 2 from regs ----
    const float* ebase = ext + (size_t)(b * N + jbase) * 8;
    float4 stA[4], stB[4];
#pragma unroll
    for (int u = 0; u < 4; u++) {
        const float* p = ebase + (size_t)(u * 64 + lane) * 8;
        stA[u] = ((const float4*)p)[0];
        stB[u] = ((const float4*)p)[1];
    }

    // adj dtype probe: high words of int64-entries 0..63 (P_false = 2^-64).
    const bool adj64 = (__any(adj[2 * lane + 1] != 0) == 0);

    // ---- weight contractions (log2e folded; exact for lrelu/masks) ----
    const float wf  = W[lane];
    const float wvf = WV[lane];
    const float c1  = wsum(wf * a[lane]) * LOG2E;
    const float c2  = wsum(wf * a[F + lane]) * LOG2E;
    const float wsf = WS[lane];
    const float cS1 = wsum(wsf * aS[lane]) * LOG2E;
    const float cS2 = wsum(wsf * aS[F + lane]) * LOG2E;

    // segmented QK contraction: group g=lane>>4 computes q_{g>>1}.k_{g&1}
    const int g = lane >> 4, l16 = lane & 15;
    const float QS = 0.25f * LOG2E;
    float prod = WQ[(g >> 1) * 16 + l16] * WK[(g & 1) * 16 + l16];
    prod = hsum16(prod);
    const float a00 = __shfl(prod, 0, 64) * QS;
    const float a01 = __shfl(prod, 16, 64) * QS;
    const float a10 = __shfl(prod, 32, 64) * QS;
    const float a11 = __shfl(prod, 48, 64) * QS;

    const int row0 = b * N + i0;
    const float x0 = input[row0], x1 = input[row0 + 1];
    const float y0 = side[row0],  y1 = side[row0 + 1];
    float ei0[8], ei1[8];
    ld8f(ext + (size_t)row0 * 8, ei0);
    ld8f(ext + (size_t)(row0 + 1) * 8, ei1);

    const float s10 = c1 * x0,  s11 = c1 * x1;
    const float t10 = cS1 * y0, t11 = cS1 * y1;

    const float* xp = input + b * N + jbase;
    const float* yp = side + b * N + jbase;
    const int arow0 = i0 * N + jbase;
    const int* adji0 = adj + arow0;
    const int* adji1 = adji0 + N;
    const long long* adjl0 = (const long long*)adj + arow0;
    const long long* adjl1 = adjl0 + N;

    // ---- pass 1: this wave's 256 logits for both rows ----
    float xj[4], L0[4], L1[4];
#pragma unroll
    for (int t = 0; t < 4; t++) {
        const int jj = lane + 64 * t;
        const float xv = xp[jj];
        const float yv = yp[jj];
        xj[t] = xv;
        const float z  = c2 * xv;
        const float zs = cS2 * yv;
        float u0 = s10 + z;  u0 = fmaxf(u0, 0.2f * u0);
        float v0 = t10 + zs; v0 = fmaxf(v0, 0.2f * v0);
        float u1 = s11 + z;  u1 = fmaxf(u1, 0.2f * u1);
        float v1 = t11 + zs; v1 = fmaxf(v1, 0.2f * v1);
        const float g0 = u0 + v0;
        const float g1 = u1 + v1;
        int m0, m1;
        if (adj64) { m0 = (adjl0[jj] != 0); m1 = (adjl1[jj] != 0); }
        else       { m0 = adji0[jj];        m1 = adji1[jj]; }
        L0[t] = (m0 != 0 && g0 > 0.f) ? g0 : NEGV;
        L1[t] = (m1 != 0 && g1 > 0.f) ? g1 : NEGV;
    }
    float M0 = fmaxf(fmaxf(L0[0], L0[1]), fmaxf(L0[2], L0[3]));
    float M1 = fmaxf(fmaxf(L1[0], L1[1]), fmaxf(L1[2], L1[3]));
    M0 = wmax(M0); M1 = wmax(M1);

    float s0 = 0.f, s1 = 0.f;
#pragma unroll
    for (int t = 0; t < 4; t++) {
        L0[t] = __builtin_amdgcn_exp2f(L0[t] - M0); s0 += L0[t];  // L := E
        L1[t] = __builtin_amdgcn_exp2f(L1[t] - M1); s1 += L1[t];
    }
    s0 = wsum(s0); s1 = wsum(s1);

    // ---- pass 2: unnormalized A_w, R_w; ej straight from registers ----
    float A0 = 0.f, A1 = 0.f, R0 = 0.f, R1 = 0.f;
#pragma unroll
    for (int t = 0; t < 4; t++) {
        float ej[8];
        ej[0] = stA[t].x; ej[1] = stA[t].y; ej[2] = stA[t].z; ej[3] = stA[t].w;
        ej[4] = stB[t].x; ej[5] = stB[t].y; ej[6] = stB[t].z; ej[7] = stB[t].w;

        const float qj0 = xj[t] * a10, qj1 = xj[t] * a11;
        const float qk00 = x0 * a00 + qj0, qk01 = x0 * a01 + qj1;
        const float qk10 = x1 * a00 + qj0, qk11 = x1 * a01 + qj1;

        float d0[8], d1[8];
        float dm0 = NEGV, dm1 = NEGV;
#pragma unroll
        for (int f = 0; f < 8; f++) {
            float dv0 = ei0[f] * qk00 + ej[f] * qk01;
            float dv1 = ei1[f] * qk10 + ej[f] * qk11;
            dv0 = (dv0 > 0.f) ? dv0 : NEGV;
            dv1 = (dv1 > 0.f) ? dv1 : NEGV;
            d0[f] = dv0; dm0 = fmaxf(dm0, dv0);
            d1[f] = dv1; dm1 = fmaxf(dm1, dv1);
        }
        float ds0 = 0.f, ds1 = 0.f, dot0 = 0.f, dot1 = 0.f;
#pragma unroll
        for (int f = 0; f < 8; f++) {
            const float e0 = __builtin_amdgcn_exp2f(d0[f] - dm0);
            const float e1 = __builtin_amdgcn_exp2f(d1[f] - dm1);
            ds0 += e0; dot0 += e0 * ei0[f];
            ds1 += e1; dot1 += e1 * ei1[f];
        }
        A0 += L0[t] * xj[t];
        A1 += L1[t] * xj[t];
        R0 += L0[t] * __builtin_amdgcn_rcpf(ds0) * dot0;
        R1 += L1[t] * __builtin_amdgcn_rcpf(ds1) * dot1;
    }
    A0 = wsum(A0); A1 = wsum(A1);
    R0 = wsum(R0); R1 = wsum(R1);

    // ---- cross-wave online-softmax merge (exact): one barrier ----
    if (lane == 0) {
        float* m = mrg + w * 8;
        m[0] = M0; m[1] = M1; m[2] = s0; m[3] = s1;
        m[4] = A0; m[5] = A1; m[6] = R0; m[7] = R1;
    }
    __syncthreads();

    const float Ma0 = fmaxf(mrg[0], mrg[8]);
    const float Ma1 = fmaxf(mrg[1], mrg[9]);
    const float p00 = __builtin_amdgcn_exp2f(mrg[0] - Ma0);  // NEGV-NEGV=0 -> 1
    const float p01 = __builtin_amdgcn_exp2f(mrg[8] - Ma0);
    const float p10 = __builtin_amdgcn_exp2f(mrg[1] - Ma1);
    const float p11 = __builtin_amdgcn_exp2f(mrg[9] - Ma1);
    const float inv0 = __builtin_amdgcn_rcpf(p00 * mrg[2] + p01 * mrg[10]);
    const float inv1 = __builtin_amdgcn_rcpf(p10 * mrg[3] + p11 * mrg[11]);

    const int o = row0 * F + lane;
    if (w == 0) {
        float o00 = (p00 * mrg[4] + p01 * mrg[12]) * inv0 * wf;
        float o01 = (p10 * mrg[5] + p11 * mrg[13]) * inv1 * wf;
        o00 = (o00 > 0.f) ? o00 : (__builtin_amdgcn_exp2f(o00 * LOG2E) - 1.f);
        o01 = (o01 > 0.f) ? o01 : (__builtin_amdgcn_exp2f(o01 * LOG2E) - 1.f);
        out[o] = o00;
        out[o + F] = o01;
    } else {
        float o10 = (p00 * mrg[6] + p01 * mrg[14]) * inv0 * wvf;
        float o11 = (p10 * mrg[7] + p11 * mrg[15]) * inv1 * wvf;
        o10 = (o10 > 0.f) ? o10 : (__builtin_amdgcn_exp2f(o10 * LOG2E) - 1.f);
        o11 = (o11 > 0.f) ? o11 : (__builtin_amdgcn_exp2f(o11 * LOG2E) - 1.f);
        out[262144 + o] = o10;      // 8*N*F
        out[262144 + o + F] = o11;
    }
}

extern "C" void kernel_launch(void* const* d_in, const int* in_sizes, int n_in,
                              void* d_out, int out_size, void* d_ws, size_t ws_size,
                              hipStream_t stream) {
    static const int exp_sizes[11] = {4096, 262144, 32768, 4096, 64, 128, 64, 128, 32, 32, 64};
    bool ok = (n_in == 11) && (out_size == 524288);
    if (ok) {
        for (int k = 0; k < 11; k++) if (in_sizes[k] != exp_sizes[k]) ok = false;
    }
    if (!ok) {
        sentinel_kernel<<<4096, 64, 0, stream>>>((float*)d_out);
        return;
    }

    gat_fused_f32<<<2048, 128, 0, stream>>>(
        (const float*)d_in[0], (const int*)d_in[1],
        (const float*)d_in[2], (const float*)d_in[3],
        (const float*)d_in[4], (const float*)d_in[5],
        (const float*)d_in[6], (const float*)d_in[7],
        (const float*)d_in[8], (const float*)d_in[9],
        (const float*)d_in[10],
        (float*)d_out);
}

// Round 9
// 14.799 us; speedup vs baseline: 1.3664x; 1.0103x over previous
//
#include <hip/hip_runtime.h>

#define NEGV (-9e15f)
#define LOG2E 1.44269504088896340736f

// ---- DPP wave-64 reductions (row_shr scan + row_bcast cross-row) ----
// ctrl must be an immediate -> template parameter.
template<int CTRL>
__device__ __forceinline__ float dpp_add(float v) {
    // old=0: lanes with no valid source contribute 0 to the sum.
    const int t = __builtin_amdgcn_update_dpp(0, __float_as_int(v), CTRL, 0xf, 0xf, false);
    return v + __int_as_float(t);
}
template<int CTRL>
__device__ __forceinline__ float dpp_fmax(float v) {
    // old=v: lanes with no valid source do fmax(v,v)=v.
    const int t = __builtin_amdgcn_update_dpp(__float_as_int(v), __float_as_int(v),
                                              CTRL, 0xf, 0xf, false);
    return fmaxf(v, __int_as_float(t));
}
__device__ __forceinline__ float rdlane(float v, int l) {
    return __int_as_float(__builtin_amdgcn_readlane(__float_as_int(v), l));
}
// full-wave sum, result broadcast via SGPR
__device__ __forceinline__ float wsum(float v) {
    v = dpp_add<0x111>(v);  // row_shr:1
    v = dpp_add<0x112>(v);  // row_shr:2
    v = dpp_add<0x114>(v);  // row_shr:4
    v = dpp_add<0x118>(v);  // row_shr:8  -> lane15 of each row = row sum
    v = dpp_add<0x142>(v);  // row_bcast15
    v = dpp_add<0x143>(v);  // row_bcast31 -> lane63 = total
    return rdlane(v, 63);
}
__device__ __forceinline__ float wmax(float v) {
    v = dpp_fmax<0x111>(v);
    v = dpp_fmax<0x112>(v);
    v = dpp_fmax<0x114>(v);
    v = dpp_fmax<0x118>(v);
    v = dpp_fmax<0x142>(v);
    v = dpp_fmax<0x143>(v);
    return rdlane(v, 63);
}
// 16-lane-segment inclusive scan; lane 15+16g holds sum of group g
__device__ __forceinline__ float rowscan16(float v) {
    v = dpp_add<0x111>(v);
    v = dpp_add<0x112>(v);
    v = dpp_add<0x114>(v);
    v = dpp_add<0x118>(v);
    return v;
}
__device__ __forceinline__ void ld8f(const float* p, float* o) {
    const float4 v0 = ((const float4*)p)[0];
    const float4 v1 = ((const float4*)p)[1];
    o[0] = v0.x; o[1] = v0.y; o[2] = v0.z; o[3] = v0.w;
    o[4] = v1.x; o[5] = v1.y; o[6] = v1.z; o[7] = v1.w;
}

__global__ __launch_bounds__(64) void sentinel_kernel(float* __restrict__ out) {
    out[blockIdx.x * 64 + threadIdx.x] = 111222.0f;
}

// Block = 128 threads = 2 waves, two adjacent rows (b,i0),(b,i0+1).
// Wave w owns j in [256w,256w+256) independently; end-merge via exact
// online-softmax rescale (one barrier, 16-float LDS). ext[j] loaded once
// into registers (stA/stB) and consumed directly in pass 2.
// All wave reductions are DPP-based (~50cy vs ~210cy shfl chains).
// Inputs f32, adj int32 (int64 auto-probe), output f32.
__global__ __launch_bounds__(128, 4) void gat_fused_f32(
    const float* __restrict__ input, const int* __restrict__ adj,
    const float* __restrict__ ext, const float* __restrict__ side,
    const float* __restrict__ W, const float* __restrict__ a,
    const float* __restrict__ WS, const float* __restrict__ aS,
    const float* __restrict__ WQ, const float* __restrict__ WK,
    const float* __restrict__ WV, float* __restrict__ out)
{
    const int N = 512, F = 64;
    const int lane = threadIdx.x & 63;
    const int w = threadIdx.x >> 6;
    const int b = blockIdx.x >> 8;
    const int i0 = (blockIdx.x & 255) * 2;

    __shared__ float mrg[16];

    const int jbase = 256 * w;

    // ---- issue this wave's ext loads NOW; consumed in pass 2 from regs ----
    const float* ebase = ext + (size_t)(b * N + jbase) * 8;
    float4 stA[4], stB[4];
#pragma unroll
    for (int u = 0; u < 4; u++) {
        const float* p = ebase + (size_t)(u * 64 + lane) * 8;
        stA[u] = ((const float4*)p)[0];
        stB[u] = ((const float4*)p)[1];
    }

    // adj dtype probe: high words of int64-entries 0..63 (P_false = 2^-64).
    const bool adj64 = (__any(adj[2 * lane + 1] != 0) == 0);

    // ---- weight contractions (log2e folded; exact for lrelu/masks) ----
    const float wf  = W[lane];
    const float wvf = WV[lane];
    const float c1  = wsum(wf * a[lane]) * LOG2E;
    const float c2  = wsum(wf * a[F + lane]) * LOG2E;
    const float wsf = WS[lane];
    const float cS1 = wsum(wsf * aS[lane]) * LOG2E;
    const float cS2 = wsum(wsf * aS[F + lane]) * LOG2E;

    // segmented QK contraction: group g computes q_{g>>1}.k_{g&1};
    // 4-step DPP scan, group sums at lanes 15/31/47/63.
    const int g = lane >> 4, l16 = lane & 15;
    const float QS = 0.25f * LOG2E;
    float prod = WQ[(g >> 1) * 16 + l16] * WK[(g & 1) * 16 + l16];
    prod = rowscan16(prod);
    const float a00 = rdlane(prod, 15) * QS;
    const float a01 = rdlane(prod, 31) * QS;
    const float a10 = rdlane(prod, 47) * QS;
    const float a11 = rdlane(prod, 63) * QS;

    const int row0 = b * N + i0;
    const float x0 = input[row0], x1 = input[row0 + 1];
    const float y0 = side[row0],  y1 = side[row0 + 1];
    float ei0[8], ei1[8];
    ld8f(ext + (size_t)row0 * 8, ei0);
    ld8f(ext + (size_t)(row0 + 1) * 8, ei1);

    const float s10 = c1 * x0,  s11 = c1 * x1;
    const float t10 = cS1 * y0, t11 = cS1 * y1;

    const float* xp = input + b * N + jbase;
    const float* yp = side + b * N + jbase;
    const int arow0 = i0 * N + jbase;
    const int* adji0 = adj + arow0;
    const int* adji1 = adji0 + N;
    const long long* adjl0 = (const long long*)adj + arow0;
    const long long* adjl1 = adjl0 + N;

    // ---- pass 1: this wave's 256 logits for both rows ----
    float xj[4], L0[4], L1[4];
#pragma unroll
    for (int t = 0; t < 4; t++) {
        const int jj = lane + 64 * t;
        const float xv = xp[jj];
        const float yv = yp[jj];
        xj[t] = xv;
        const float z  = c2 * xv;
        const float zs = cS2 * yv;
        float u0 = s10 + z;  u0 = fmaxf(u0, 0.2f * u0);
        float v0 = t10 + zs; v0 = fmaxf(v0, 0.2f * v0);
        float u1 = s11 + z;  u1 = fmaxf(u1, 0.2f * u1);
        float v1 = t11 + zs; v1 = fmaxf(v1, 0.2f * v1);
        const float g0 = u0 + v0;
        const float g1 = u1 + v1;
        int m0, m1;
        if (adj64) { m0 = (adjl0[jj] != 0); m1 = (adjl1[jj] != 0); }
        else       { m0 = adji0[jj];        m1 = adji1[jj]; }
        L0[t] = (m0 != 0 && g0 > 0.f) ? g0 : NEGV;
        L1[t] = (m1 != 0 && g1 > 0.f) ? g1 : NEGV;
    }
    float M0 = fmaxf(fmaxf(L0[0], L0[1]), fmaxf(L0[2], L0[3]));
    float M1 = fmaxf(fmaxf(L1[0], L1[1]), fmaxf(L1[2], L1[3]));
    M0 = wmax(M0); M1 = wmax(M1);

    float s0 = 0.f, s1 = 0.f;
#pragma unroll
    for (int t = 0; t < 4; t++) {
        L0[t] = __builtin_amdgcn_exp2f(L0[t] - M0); s0 += L0[t];  // L := E
        L1[t] = __builtin_amdgcn_exp2f(L1[t] - M1); s1 += L1[t];
    }

    // ---- pass 2: unnormalized A_w, R_w; ej straight from registers ----
    float A0 = 0.f, A1 = 0.f, R0 = 0.f, R1 = 0.f;
#pragma unroll
    for (int t = 0; t < 4; t++) {
        float ej[8];
        ej[0] = stA[t].x; ej[1] = stA[t].y; ej[2] = stA[t].z; ej[3] = stA[t].w;
        ej[4] = stB[t].x; ej[5] = stB[t].y; ej[6] = stB[t].z; ej[7] = stB[t].w;

        const float qj0 = xj[t] * a10, qj1 = xj[t] * a11;
        const float qk00 = x0 * a00 + qj0, qk01 = x0 * a01 + qj1;
        const float qk10 = x1 * a00 + qj0, qk11 = x1 * a01 + qj1;

        float d0[8], d1[8];
        float dm0 = NEGV, dm1 = NEGV;
#pragma unroll
        for (int f = 0; f < 8; f++) {
            float dv0 = ei0[f] * qk00 + ej[f] * qk01;
            float dv1 = ei1[f] * qk10 + ej[f] * qk11;
            dv0 = (dv0 > 0.f) ? dv0 : NEGV;
            dv1 = (dv1 > 0.f) ? dv1 : NEGV;
            d0[f] = dv0; dm0 = fmaxf(dm0, dv0);
            d1[f] = dv1; dm1 = fmaxf(dm1, dv1);
        }
        float ds0 = 0.f, ds1 = 0.f, dot0 = 0.f, dot1 = 0.f;
#pragma unroll
        for (int f = 0; f < 8; f++) {
            const float e0 = __builtin_amdgcn_exp2f(d0[f] - dm0);
            const float e1 = __builtin_amdgcn_exp2f(d1[f] - dm1);
            ds0 += e0; dot0 += e0 * ei0[f];
            ds1 += e1; dot1 += e1 * ei1[f];
        }
        A0 += L0[t] * xj[t];
        A1 += L1[t] * xj[t];
        R0 += L0[t] * __builtin_amdgcn_rcpf(ds0) * dot0;
        R1 += L1[t] * __builtin_amdgcn_rcpf(ds1) * dot1;
    }
    // four independent DPP reduce chains (interleaved by the scheduler)
    s0 = wsum(s0); s1 = wsum(s1);
    A0 = wsum(A0); A1 = wsum(A1);
    R0 = wsum(R0); R1 = wsum(R1);

    // ---- cross-wave online-softmax merge (exact): one barrier ----
    if (lane == 0) {
        float* m = mrg + w * 8;
        m[0] = M0; m[1] = M1; m[2] = s0; m[3] = s1;
        m[4] = A0; m[5] = A1; m[6] = R0; m[7] = R1;
    }
    __syncthreads();

    const float Ma0 = fmaxf(mrg[0], mrg[8]);
    const float Ma1 = fmaxf(mrg[1], mrg[9]);
    const float p00 = __builtin_amdgcn_exp2f(mrg[0] - Ma0);  // NEGV-NEGV=0 -> 1
    const float p01 = __builtin_amdgcn_exp2f(mrg[8] - Ma0);
    const float p10 = __builtin_amdgcn_exp2f(mrg[1] - Ma1);
    const float p11 = __builtin_amdgcn_exp2f(mrg[9] - Ma1);
    const float inv0 = __builtin_amdgcn_rcpf(p00 * mrg[2] + p01 * mrg[10]);
    const float inv1 = __builtin_amdgcn_rcpf(p10 * mrg[3] + p11 * mrg[11]);

    const int o = row0 * F + lane;
    if (w == 0) {
        float o00 = (p00 * mrg[4] + p01 * mrg[12]) * inv0 * wf;
        float o01 = (p10 * mrg[5] + p11 * mrg[13]) * inv1 * wf;
        o00 = (o00 > 0.f) ? o00 : (__builtin_amdgcn_exp2f(o00 * LOG2E) - 1.f);
        o01 = (o01 > 0.f) ? o01 : (__builtin_amdgcn_exp2f(o01 * LOG2E) - 1.f);
        out[o] = o00;
        out[o + F] = o01;
    } else {
        float o10 = (p00 * mrg[6] + p01 * mrg[14]) * inv0 * wvf;
        float o11 = (p10 * mrg[7] + p11 * mrg[15]) * inv1 * wvf;
        o10 = (o10 > 0.f) ? o10 : (__builtin_amdgcn_exp2f(o10 * LOG2E) - 1.f);
        o11 = (o11 > 0.f) ? o11 : (__builtin_amdgcn_exp2f(o11 * LOG2E) - 1.f);
        out[262144 + o] = o10;      // 8*N*F
        out[262144 + o + F] = o11;
    }
}

extern "C" void kernel_launch(void* const* d_in, const int* in_sizes, int n_in,
                              void* d_out, int out_size, void* d_ws, size_t ws_size,
                              hipStream_t stream) {
    static const int exp_sizes[11] = {4096, 262144, 32768, 4096, 64, 128, 64, 128, 32, 32, 64};
    bool ok = (n_in == 11) && (out_size == 524288);
    if (ok) {
        for (int k = 0; k < 11; k++) if (in_sizes[k] != exp_sizes[k]) ok = false;
    }
    if (!ok) {
        sentinel_kernel<<<4096, 64, 0, stream>>>((float*)d_out);
        return;
    }

    gat_fused_f32<<<2048, 128, 0, stream>>>(
        (const float*)d_in[0], (const int*)d_in[1],
        (const float*)d_in[2], (const float*)d_in[3],
        (const float*)d_in[4], (const float*)d_in[5],
        (const float*)d_in[6], (const float*)d_in[7],
        (const float*)d_in[8], (const float*)d_in[9],
        (const float*)d_in[10],
        (float*)d_out);
}